// Round 6
// baseline (1435.720 us; speedup 1.0000x reference)
//
#include <hip/hip_runtime.h>
#include <hip/hip_bf16.h>

#define HW 16384   // 128*128
#define W_ 128
#define PS 16900   // padded plane stride = 130*130
#define RS 130     // padded row stride
#define ORG 131    // interior origin (1*130+1)
#define GSZ 9264   // padded per-group DCN weight slab

// ---------------------------------------------------------------------------
// transpose conv weight w[oc][cin][3][3] -> wTb[cin][zb][54], row idx = tap*6+j
// (54 contiguous floats per (cin, oc-block) -> wide scalar loads in conv)
// ---------------------------------------------------------------------------
__global__ void transpose_wc(const float* __restrict__ w, float* __restrict__ wTb,
                             int CIN, int Cout, int ZB) {
    int i = blockIdx.x * 256 + threadIdx.x;
    int total = CIN * ZB * 54;
    if (i >= total) return;
    int r = i % 54;
    int t2 = i / 54;
    int zb = t2 % ZB;
    int cin = t2 / ZB;
    int tap = r / 6, j = r % 6;
    int oc = zb * 6 + j;
    wTb[i] = (oc < Cout) ? w[(oc * CIN + cin) * 9 + tap] : 0.f;
}

// ---------------------------------------------------------------------------
// transpose w_d (96,32,3,3) -> wT[g][(c*9+k)*32 + (c>>3)*4 + o]  (bank-staggered)
// ---------------------------------------------------------------------------
__global__ void transpose_wd(const float* __restrict__ w_d,
                             float* __restrict__ wT) {
    int i = blockIdx.x * 256 + threadIdx.x;       // 27648 total
    if (i >= 27648) return;
    int o = i & 31;
    int t = i >> 5;
    int k = t % 9; t /= 9;
    int c = t & 31;
    int g = t >> 5;
    wT[g * GSZ + ((c * 9 + k) << 5) + ((c >> 3) << 2) + o] =
        w_d[((g * 32 + o) * 32 + c) * 9 + k];
}

// ---------------------------------------------------------------------------
// Bottom conv: cat(X1,X2) 192 -> 96 ch into PADDED featA.  Clamped in-plane
// tap offsets (inputs are harness-owned; never OOB), masked lanes -> 0.
// Prefetch distance 2 (3 rotating reg buffers); contiguous 54-float weight
// rows -> batched s_loads.  Grid 8x32x16 = 4096 waves.
// ---------------------------------------------------------------------------
__global__ __launch_bounds__(64) void conv_bot_k(const float* __restrict__ X1,
                                                 const float* __restrict__ X2,
                                                 const float* __restrict__ wTb,
                                                 float* __restrict__ out) {
    const int tx = threadIdx.x & 15;
    const int ty = threadIdx.x >> 4;
    const int px = (blockIdx.x << 4) + tx;
    const int py = (blockIdx.y << 2) + ty;
    const int zb = __builtin_amdgcn_readfirstlane(blockIdx.z);

    int toff[9];
    bool vm[9];
#pragma unroll
    for (int t = 0; t < 9; ++t) {
        int dy = t / 3 - 1, dx = t % 3 - 1;
        int yy = min(max(py + dy, 0), 127);
        int xx = min(max(px + dx, 0), 127);
        toff[t] = yy * W_ + xx;
        vm[t] = ((unsigned)(py + dy) < 128u) & ((unsigned)(px + dx) < 128u);
    }

    float acc[6];
#pragma unroll
    for (int j = 0; j < 6; ++j) acc[j] = 0.f;

    float b0[9], b1[9], b2[9];
    const float* wr = wTb + zb * 54;

#define PLB(i) ((i) < 96 ? X1 + (i) * HW : X2 + ((i) - 96) * HW)
#define LDB(buf, pl) { const float* _p = (pl); _Pragma("unroll") \
    for (int t = 0; t < 9; ++t) { float _ld = _p[toff[t]]; buf[t] = vm[t] ? _ld : 0.f; } }
#define FMB(buf, wrp) { _Pragma("unroll") for (int t = 0; t < 9; ++t) { \
    _Pragma("unroll") for (int j = 0; j < 6; ++j) acc[j] += buf[t] * (wrp)[t * 6 + j]; } }

    LDB(b0, PLB(0));
    LDB(b1, PLB(1));
#pragma unroll 1
    for (int c = 0; c < 192; c += 3) {
        LDB(b2, PLB(min(c + 2, 191))); FMB(b0, wr); wr += 16 * 54;
        LDB(b0, PLB(min(c + 3, 191))); FMB(b1, wr); wr += 16 * 54;
        LDB(b1, PLB(min(c + 4, 191))); FMB(b2, wr); wr += 16 * 54;
    }
#undef PLB

    const int po = py * RS + px + ORG;
#pragma unroll
    for (int j = 0; j < 6; ++j)
        out[(zb * 6 + j) * PS + po] = acc[j];
}

// ---------------------------------------------------------------------------
// Offset conv: PADDED feat 96 -> 81 ch (flat out).  No masks (borders are
// zero), pure imm-offset taps.  Prefetch distance 2.  Grid 8x32x14.
// ---------------------------------------------------------------------------
__global__ __launch_bounds__(64) void conv_off_k(const float* __restrict__ in,
                                                 const float* __restrict__ wTb,
                                                 float* __restrict__ out) {
    const int tx = threadIdx.x & 15;
    const int ty = threadIdx.x >> 4;
    const int px = (blockIdx.x << 4) + tx;
    const int py = (blockIdx.y << 2) + ty;
    const int zb = __builtin_amdgcn_readfirstlane(blockIdx.z);

    const float* bc = in + py * RS + px + ORG;
    const float* wr = wTb + zb * 54;

    float acc[6];
#pragma unroll
    for (int j = 0; j < 6; ++j) acc[j] = 0.f;

    float b0[9], b1[9], b2[9];

#define LDO(buf, pli) { const float* _p = bc + (size_t)min(pli, 95) * PS; _Pragma("unroll") \
    for (int t = 0; t < 9; ++t) { buf[t] = _p[(t / 3 - 1) * RS + (t % 3 - 1)]; } }

    LDO(b0, 0);
    LDO(b1, 1);
#pragma unroll 1
    for (int c = 0; c < 96; c += 3) {
        LDO(b2, c + 2); FMB(b0, wr); wr += 14 * 54;
        LDO(b0, c + 3); FMB(b1, wr); wr += 14 * 54;
        LDO(b1, c + 4); FMB(b2, wr); wr += 14 * 54;
    }

    const int p = py * W_ + px;
#pragma unroll
    for (int j = 0; j < 6; ++j) {
        int ocg = zb * 6 + j;
        if (ocg < 81) out[ocg * HW + p] = acc[j];
    }
}

// ---------------------------------------------------------------------------
// Modulated deformable conv (DCNv2), groups=3, Cg=32, K=9.
// Block: 256 thr = 32 pixels x 8 c-subsets (4 ch each); blockIdx.y = group.
// Grid 512x3 = 1536 blocks.  Reads PADDED feat; writes padded (layers 0-2)
// or flat d_out (layer 3).  8-lane shfl_xor reduction over the c-split.
// ---------------------------------------------------------------------------
__global__ __launch_bounds__(256) void dcn_kernel(const float* __restrict__ feat,
                                                  const float* __restrict__ off_raw,
                                                  const float* __restrict__ wT,
                                                  const float* __restrict__ b_d,
                                                  float* __restrict__ out,
                                                  int padded) {
    __shared__ float s_w[GSZ];

    const int g = blockIdx.y;
    {
        const float4* src = (const float4*)(wT + g * GSZ);
        float4* dst = (float4*)s_w;
        for (int i = threadIdx.x; i < GSZ / 4; i += 256) dst[i] = src[i];
    }
    __syncthreads();

    const int tid = threadIdx.x;
    const int csub = tid & 7;
    const int lp = tid >> 3;
    const int p = blockIdx.x * 32 + lp;
    const int y = p >> 7, x = p & 127;
    const float* fgo = feat + g * 32 * PS + ORG;
    const int cbase = csub * 4;

    // preload all offsets/masks (27 outstanding loads; broadcast across csubs)
    float dyv[9], dxv[9], mrv[9];
#pragma unroll
    for (int k = 0; k < 9; ++k) {
        const int offch = g * 9 + k;
        dyv[k] = off_raw[offch * HW + p];
        dxv[k] = off_raw[(27 + offch) * HW + p];
        mrv[k] = off_raw[(54 + offch) * HW + p];
    }

    float acc[32];
#pragma unroll
    for (int o = 0; o < 32; ++o) acc[o] = 0.f;

#pragma unroll
    for (int k = 0; k < 9; ++k) {
        float m = 1.f / (1.f + __expf(-mrv[k]));

        float py = dyv[k] + (float)y + (float)(k / 3 - 1);
        float px = dxv[k] + (float)x + (float)(k % 3 - 1);
        float y0f = floorf(py), x0f = floorf(px);
        float fy = py - y0f, fx = px - x0f;

        float vy0 = (y0f >= 0.f   && y0f <= 127.f) ? 1.f : 0.f;
        float vy1 = (y0f >= -1.f  && y0f <= 126.f) ? 1.f : 0.f;
        float vx0 = (x0f >= 0.f   && x0f <= 127.f) ? 1.f : 0.f;
        float vx1 = (x0f >= -1.f  && x0f <= 126.f) ? 1.f : 0.f;

        int iy0r = (int)y0f, ix0r = (int)x0f;
        int iy0 = min(max(iy0r, 0), 127);
        int iy1 = min(max(iy0r + 1, 0), 127);
        int ix0 = min(max(ix0r, 0), 127);
        int ix1 = min(max(ix0r + 1, 0), 127);

        float w00 = (1.f - fy) * (1.f - fx) * vy0 * vx0 * m;
        float w01 = (1.f - fy) * fx        * vy0 * vx1 * m;
        float w10 = fy        * (1.f - fx) * vy1 * vx0 * m;
        float w11 = fy        * fx         * vy1 * vx1 * m;

        int o00 = iy0 * RS + ix0, o01 = iy0 * RS + ix1;
        int o10 = iy1 * RS + ix0, o11 = iy1 * RS + ix1;

#pragma unroll
        for (int c4 = 0; c4 < 4; ++c4) {
            int c = cbase + c4;
            const float* fc = fgo + c * PS;
            float v = w00 * fc[o00] + w01 * fc[o01] + w10 * fc[o10] + w11 * fc[o11];
            const float4* wv = (const float4*)&s_w[((c * 9 + k) << 5) + ((c >> 3) << 2)];
#pragma unroll
            for (int j = 0; j < 8; ++j) {
                float4 ww = wv[j];
                acc[4 * j + 0] += v * ww.x;
                acc[4 * j + 1] += v * ww.y;
                acc[4 * j + 2] += v * ww.z;
                acc[4 * j + 3] += v * ww.w;
            }
        }
    }

    // reduce the c-split across the 8 csub lanes (same pixel)
#pragma unroll
    for (int o = 0; o < 32; ++o) {
        acc[o] += __shfl_xor(acc[o], 1);
        acc[o] += __shfl_xor(acc[o], 2);
        acc[o] += __shfl_xor(acc[o], 4);
    }

    // each lane writes its 4 channels (static acc indices via binary select)
#pragma unroll
    for (int j = 0; j < 4; ++j) {
        float s0a = (csub & 1) ? acc[4 + j]  : acc[j];
        float s0b = (csub & 1) ? acc[12 + j] : acc[8 + j];
        float s0c = (csub & 1) ? acc[20 + j] : acc[16 + j];
        float s0d = (csub & 1) ? acc[28 + j] : acc[24 + j];
        float s1a = (csub & 2) ? s0b : s0a;
        float s1b = (csub & 2) ? s0d : s0c;
        float v   = (csub & 4) ? s1b : s1a;
        int ch = g * 32 + cbase + j;
        float ov = v + b_d[ch];
        if (padded) out[ch * PS + y * RS + x + ORG] = ov;
        else        out[ch * HW + p] = ov;
    }
}

// ---------------------------------------------------------------------------
extern "C" void kernel_launch(void* const* d_in, const int* in_sizes, int n_in,
                              void* d_out, int out_size, void* d_ws, size_t ws_size,
                              hipStream_t stream) {
    const float* X1    = (const float*)d_in[0];
    const float* X2    = (const float*)d_in[1];
    const float* w_bot = (const float*)d_in[2];
    const float* w_off[4] = {(const float*)d_in[3], (const float*)d_in[6],
                             (const float*)d_in[9], (const float*)d_in[12]};
    const float* w_d[4]   = {(const float*)d_in[4], (const float*)d_in[7],
                             (const float*)d_in[10], (const float*)d_in[13]};
    const float* b_d[4]   = {(const float*)d_in[5], (const float*)d_in[8],
                             (const float*)d_in[11], (const float*)d_in[14]};

    float* ws = (float*)d_ws;
    // layout (floats):
    const int PADF = 96 * PS;                    // 1,622,400
    float* featA   = ws;                         // padded
    float* featB   = ws + PADF;                  // padded
    float* off_raw = ws + 2 * PADF;              // 81*HW = 1,327,104
    float* wTb_bot = off_raw + 81 * HW;          // 192*16*54 = 165,888
    float* wTb_off = wTb_bot + 192 * 16 * 54;    // 96*14*54  = 72,576
    float* wTd     = wTb_off + 96 * 14 * 54;     // 3*GSZ     = 27,792
    // total 4,838,160 floats = 19.35 MB

    // zero both padded feat buffers (borders must be 0; interiors overwritten)
    hipMemsetAsync(featA, 0, (size_t)2 * PADF * sizeof(float), stream);

    transpose_wc<<<(192 * 16 * 54 + 255) / 256, 256, 0, stream>>>(w_bot, wTb_bot, 192, 96, 16);
    conv_bot_k<<<dim3(8, 32, 16), 64, 0, stream>>>(X1, X2, wTb_bot, featA);

    float* cur = featA;
    float* nxt = featB;
    for (int it = 0; it < 4; ++it) {
        transpose_wc<<<(96 * 14 * 54 + 255) / 256, 256, 0, stream>>>(w_off[it], wTb_off, 96, 81, 14);
        conv_off_k<<<dim3(8, 32, 14), 64, 0, stream>>>(cur, wTb_off, off_raw);
        transpose_wd<<<108, 256, 0, stream>>>(w_d[it], wTd);
        float* outp = (it == 3) ? (float*)d_out : nxt;
        dcn_kernel<<<dim3(512, 3), 256, 0, stream>>>(cur, off_raw, wTd, b_d[it],
                                                     outp, it == 3 ? 0 : 1);
        float* t = cur; cur = nxt; nxt = t;
    }
}

// Round 7
// 510.070 us; speedup vs baseline: 2.8147x; 2.8147x over previous
//
#include <hip/hip_runtime.h>
#include <hip/hip_bf16.h>

#define HW 16384   // 128*128
#define W_ 128
#define PS 16900   // padded plane stride = 130*130
#define RS 130     // padded row stride
#define ORG 131    // interior origin (1*130+1)
#define GSZ 9264   // padded per-group DCN weight slab

// ---------------------------------------------------------------------------
// transpose conv weight w[oc][cin][3][3] -> wTb[cin][zb][54], row idx = tap*6+j
// (54 contiguous floats per (cin, oc-block) -> wide scalar loads in conv)
// ---------------------------------------------------------------------------
__global__ void transpose_wc(const float* __restrict__ w, float* __restrict__ wTb,
                             int CIN, int Cout, int ZB) {
    int i = blockIdx.x * 256 + threadIdx.x;
    int total = CIN * ZB * 54;
    if (i >= total) return;
    int r = i % 54;
    int t2 = i / 54;
    int zb = t2 % ZB;
    int cin = t2 / ZB;
    int tap = r / 6, j = r % 6;
    int oc = zb * 6 + j;
    wTb[i] = (oc < Cout) ? w[(oc * CIN + cin) * 9 + tap] : 0.f;
}

// ---------------------------------------------------------------------------
// transpose w_d (96,32,3,3) -> wT[g][(c*9+k)*32 + (c>>3)*4 + o]  (bank-staggered)
// ---------------------------------------------------------------------------
__global__ void transpose_wd(const float* __restrict__ w_d,
                             float* __restrict__ wT) {
    int i = blockIdx.x * 256 + threadIdx.x;       // 27648 total
    if (i >= 27648) return;
    int o = i & 31;
    int t = i >> 5;
    int k = t % 9; t /= 9;
    int c = t & 31;
    int g = t >> 5;
    wT[g * GSZ + ((c * 9 + k) << 5) + ((c >> 3) << 2) + o] =
        w_d[((g * 32 + o) * 32 + c) * 9 + k];
}

// ---------------------------------------------------------------------------
// Bottom conv: cat(X1,X2) 192 -> 96 ch into PADDED featA.  Clamped in-plane
// tap offsets (inputs are harness-owned; never OOB), masked lanes -> 0.
// Prefetch distance 2 (3 rotating reg buffers); contiguous 54-float weight
// rows -> batched s_loads.  Grid 8x32x16 = 4096 waves.
// ---------------------------------------------------------------------------
__global__ __launch_bounds__(64) void conv_bot_k(const float* __restrict__ X1,
                                                 const float* __restrict__ X2,
                                                 const float* __restrict__ wTb,
                                                 float* __restrict__ out) {
    const int tx = threadIdx.x & 15;
    const int ty = threadIdx.x >> 4;
    const int px = (blockIdx.x << 4) + tx;
    const int py = (blockIdx.y << 2) + ty;
    const int zb = __builtin_amdgcn_readfirstlane(blockIdx.z);

    int toff[9];
    bool vm[9];
#pragma unroll
    for (int t = 0; t < 9; ++t) {
        int dy = t / 3 - 1, dx = t % 3 - 1;
        int yy = min(max(py + dy, 0), 127);
        int xx = min(max(px + dx, 0), 127);
        toff[t] = yy * W_ + xx;
        vm[t] = ((unsigned)(py + dy) < 128u) & ((unsigned)(px + dx) < 128u);
    }

    float acc[6];
#pragma unroll
    for (int j = 0; j < 6; ++j) acc[j] = 0.f;

    float b0[9], b1[9], b2[9];
    const float* wr = wTb + zb * 54;

#define PLB(i) ((i) < 96 ? X1 + (i) * HW : X2 + ((i) - 96) * HW)
#define LDB(buf, pl) { const float* _p = (pl); _Pragma("unroll") \
    for (int t = 0; t < 9; ++t) { float _ld = _p[toff[t]]; buf[t] = vm[t] ? _ld : 0.f; } }
#define FMB(buf, wrp) { _Pragma("unroll") for (int t = 0; t < 9; ++t) { \
    _Pragma("unroll") for (int j = 0; j < 6; ++j) acc[j] += buf[t] * (wrp)[t * 6 + j]; } }

    LDB(b0, PLB(0));
    LDB(b1, PLB(1));
#pragma unroll 1
    for (int c = 0; c < 192; c += 3) {
        LDB(b2, PLB(min(c + 2, 191))); FMB(b0, wr); wr += 16 * 54;
        LDB(b0, PLB(min(c + 3, 191))); FMB(b1, wr); wr += 16 * 54;
        LDB(b1, PLB(min(c + 4, 191))); FMB(b2, wr); wr += 16 * 54;
    }
#undef PLB

    const int po = py * RS + px + ORG;
#pragma unroll
    for (int j = 0; j < 6; ++j)
        out[(zb * 6 + j) * PS + po] = acc[j];
}

// ---------------------------------------------------------------------------
// Offset conv: PADDED feat 96 -> 81 ch (flat out).  No masks (borders are
// zero), pure imm-offset taps.  Prefetch distance 2.  Grid 8x32x14.
// ---------------------------------------------------------------------------
__global__ __launch_bounds__(64) void conv_off_k(const float* __restrict__ in,
                                                 const float* __restrict__ wTb,
                                                 float* __restrict__ out) {
    const int tx = threadIdx.x & 15;
    const int ty = threadIdx.x >> 4;
    const int px = (blockIdx.x << 4) + tx;
    const int py = (blockIdx.y << 2) + ty;
    const int zb = __builtin_amdgcn_readfirstlane(blockIdx.z);

    const float* bc = in + py * RS + px + ORG;
    const float* wr = wTb + zb * 54;

    float acc[6];
#pragma unroll
    for (int j = 0; j < 6; ++j) acc[j] = 0.f;

    float b0[9], b1[9], b2[9];

#define LDO(buf, pli) { const float* _p = bc + (size_t)min(pli, 95) * PS; _Pragma("unroll") \
    for (int t = 0; t < 9; ++t) { buf[t] = _p[(t / 3 - 1) * RS + (t % 3 - 1)]; } }

    LDO(b0, 0);
    LDO(b1, 1);
#pragma unroll 1
    for (int c = 0; c < 96; c += 3) {
        LDO(b2, c + 2); FMB(b0, wr); wr += 14 * 54;
        LDO(b0, c + 3); FMB(b1, wr); wr += 14 * 54;
        LDO(b1, c + 4); FMB(b2, wr); wr += 14 * 54;
    }

    const int p = py * W_ + px;
#pragma unroll
    for (int j = 0; j < 6; ++j) {
        int ocg = zb * 6 + j;
        if (ocg < 81) out[ocg * HW + p] = acc[j];
    }
}

// ---------------------------------------------------------------------------
// Modulated deformable conv (DCNv2), groups=3, Cg=32, K=9.  (r5-proven shape)
// Block: 256 thr = 64 pixels x 4 c-subsets (8 ch each); blockIdx.y = group.
// Grid 256x3.  XCD-aware pixel-block swizzle: each XCD gets a contiguous
// 16-row band -> gathers are L2-resident.  Conflict-free 16B-staggered LDS
// weights; 16-consecutive-pixel (64B) coalesced stores.
// Reads PADDED feat; writes padded (layers 0-2) or flat d_out (layer 3).
// ---------------------------------------------------------------------------
__global__ __launch_bounds__(256) void dcn_kernel(const float* __restrict__ feat,
                                                  const float* __restrict__ off_raw,
                                                  const float* __restrict__ wT,
                                                  const float* __restrict__ b_d,
                                                  float* __restrict__ out,
                                                  int padded) {
    __shared__ float s_w[GSZ];

    const int g = blockIdx.y;
    {
        const float4* src = (const float4*)(wT + g * GSZ);
        float4* dst = (float4*)s_w;
        for (int i = threadIdx.x; i < GSZ / 4; i += 256) dst[i] = src[i];
    }
    __syncthreads();

    const int tid = threadIdx.x;
    const int csub = tid & 3;
    const int lp = tid >> 2;
    // XCD swizzle (256 blocks = 8 xcd x 32 chunks): xcd k -> pixel rows [16k,16k+16)
    const int pb = ((blockIdx.x & 7) << 5) + (blockIdx.x >> 3);
    const int p = pb * 64 + lp;
    const int y = p >> 7, x = p & 127;
    const float* fgo = feat + g * 32 * PS + ORG;
    const int cbase = csub * 8;

    // preload all offsets/masks (27 outstanding loads)
    float dyv[9], dxv[9], mrv[9];
#pragma unroll
    for (int k = 0; k < 9; ++k) {
        const int offch = g * 9 + k;
        dyv[k] = off_raw[offch * HW + p];
        dxv[k] = off_raw[(27 + offch) * HW + p];
        mrv[k] = off_raw[(54 + offch) * HW + p];
    }

    float acc[32];
#pragma unroll
    for (int o = 0; o < 32; ++o) acc[o] = 0.f;

#pragma unroll
    for (int k = 0; k < 9; ++k) {
        float m = 1.f / (1.f + __expf(-mrv[k]));

        float py = dyv[k] + (float)y + (float)(k / 3 - 1);
        float px = dxv[k] + (float)x + (float)(k % 3 - 1);
        float y0f = floorf(py), x0f = floorf(px);
        float fy = py - y0f, fx = px - x0f;

        float vy0 = (y0f >= 0.f   && y0f <= 127.f) ? 1.f : 0.f;
        float vy1 = (y0f >= -1.f  && y0f <= 126.f) ? 1.f : 0.f;
        float vx0 = (x0f >= 0.f   && x0f <= 127.f) ? 1.f : 0.f;
        float vx1 = (x0f >= -1.f  && x0f <= 126.f) ? 1.f : 0.f;

        int iy0r = (int)y0f, ix0r = (int)x0f;
        int iy0 = min(max(iy0r, 0), 127);
        int iy1 = min(max(iy0r + 1, 0), 127);
        int ix0 = min(max(ix0r, 0), 127);
        int ix1 = min(max(ix0r + 1, 0), 127);

        float w00 = (1.f - fy) * (1.f - fx) * vy0 * vx0 * m;
        float w01 = (1.f - fy) * fx        * vy0 * vx1 * m;
        float w10 = fy        * (1.f - fx) * vy1 * vx0 * m;
        float w11 = fy        * fx         * vy1 * vx1 * m;

        int o00 = iy0 * RS + ix0, o01 = iy0 * RS + ix1;
        int o10 = iy1 * RS + ix0, o11 = iy1 * RS + ix1;

#pragma unroll
        for (int c8 = 0; c8 < 8; ++c8) {
            int c = cbase + c8;
            const float* fc = fgo + c * PS;
            float v = w00 * fc[o00] + w01 * fc[o01] + w10 * fc[o10] + w11 * fc[o11];
            const float4* wv = (const float4*)&s_w[((c * 9 + k) << 5) + ((c >> 3) << 2)];
#pragma unroll
            for (int j = 0; j < 8; ++j) {
                float4 ww = wv[j];
                acc[4 * j + 0] += v * ww.x;
                acc[4 * j + 1] += v * ww.y;
                acc[4 * j + 2] += v * ww.z;
                acc[4 * j + 3] += v * ww.w;
            }
        }
    }

    // reduce the c-split across the 4 csub lanes (same pixel)
#pragma unroll
    for (int o = 0; o < 32; ++o) {
        acc[o] += __shfl_xor(acc[o], 1);
        acc[o] += __shfl_xor(acc[o], 2);
    }

    // each lane writes its 8 channels (static acc indices)
#pragma unroll
    for (int j = 0; j < 8; ++j) {
        float vj = (csub == 0) ? acc[j]
                 : (csub == 1) ? acc[8 + j]
                 : (csub == 2) ? acc[16 + j]
                 :               acc[24 + j];
        int ch = g * 32 + csub * 8 + j;
        float ov = vj + b_d[ch];
        if (padded) out[ch * PS + y * RS + x + ORG] = ov;
        else        out[ch * HW + p] = ov;
    }
}

// ---------------------------------------------------------------------------
extern "C" void kernel_launch(void* const* d_in, const int* in_sizes, int n_in,
                              void* d_out, int out_size, void* d_ws, size_t ws_size,
                              hipStream_t stream) {
    const float* X1    = (const float*)d_in[0];
    const float* X2    = (const float*)d_in[1];
    const float* w_bot = (const float*)d_in[2];
    const float* w_off[4] = {(const float*)d_in[3], (const float*)d_in[6],
                             (const float*)d_in[9], (const float*)d_in[12]};
    const float* w_d[4]   = {(const float*)d_in[4], (const float*)d_in[7],
                             (const float*)d_in[10], (const float*)d_in[13]};
    const float* b_d[4]   = {(const float*)d_in[5], (const float*)d_in[8],
                             (const float*)d_in[11], (const float*)d_in[14]};

    float* ws = (float*)d_ws;
    // layout (floats):
    const int PADF = 96 * PS;                    // 1,622,400
    float* featA   = ws;                         // padded
    float* featB   = ws + PADF;                  // padded
    float* off_raw = ws + 2 * PADF;              // 81*HW = 1,327,104
    float* wTb_bot = off_raw + 81 * HW;          // 192*16*54 = 165,888
    float* wTb_off = wTb_bot + 192 * 16 * 54;    // 96*14*54  = 72,576
    float* wTd     = wTb_off + 96 * 14 * 54;     // 3*GSZ     = 27,792
    // total 4,838,160 floats = 19.35 MB

    // zero both padded feat buffers (borders must be 0; interiors overwritten)
    hipMemsetAsync(featA, 0, (size_t)2 * PADF * sizeof(float), stream);

    transpose_wc<<<(192 * 16 * 54 + 255) / 256, 256, 0, stream>>>(w_bot, wTb_bot, 192, 96, 16);
    conv_bot_k<<<dim3(8, 32, 16), 64, 0, stream>>>(X1, X2, wTb_bot, featA);

    float* cur = featA;
    float* nxt = featB;
    for (int it = 0; it < 4; ++it) {
        transpose_wc<<<(96 * 14 * 54 + 255) / 256, 256, 0, stream>>>(w_off[it], wTb_off, 96, 81, 14);
        conv_off_k<<<dim3(8, 32, 14), 64, 0, stream>>>(cur, wTb_off, off_raw);
        transpose_wd<<<108, 256, 0, stream>>>(w_d[it], wTd);
        float* outp = (it == 3) ? (float*)d_out : nxt;
        dcn_kernel<<<dim3(256, 3), 256, 0, stream>>>(cur, off_raw, wTd, b_d[it],
                                                     outp, it == 3 ? 0 : 1);
        float* t = cur; cur = nxt; nxt = t;
    }
}

// Round 8
// 206.491 us; speedup vs baseline: 6.9529x; 2.4702x over previous
//
#include <hip/hip_runtime.h>

#define HW 16384   // 128*128
#define W_ 128
#define RSB 130    // padded row stride (pixels)
#define GSZ 9264   // padded per-group DCN weight slab (floats)

typedef short short8 __attribute__((ext_vector_type(8)));
typedef float f32x4 __attribute__((ext_vector_type(4)));
typedef unsigned short ushort8v __attribute__((ext_vector_type(8)));

__device__ __forceinline__ float b2f(unsigned short u) {
    return __uint_as_float(((unsigned)u) << 16);
}
__device__ __forceinline__ unsigned short f2b(float f) {
    unsigned u = __float_as_uint(f);
    return (unsigned short)((u + 0x7fffu + ((u >> 16) & 1u)) >> 16);
}

// ---------------------------------------------------------------------------
// pack cat(X1[0], X2[0]) -> padded NHWC bf16 (192 ch), borders pre-zeroed
// ---------------------------------------------------------------------------
__global__ __launch_bounds__(256) void pack_nhwc(const float* __restrict__ X1,
                                                 const float* __restrict__ X2,
                                                 unsigned short* __restrict__ dst) {
    int i = blockIdx.x * 256 + threadIdx.x;      // 16384*24
    int p = i & (HW - 1);
    int cb = i >> 14;
    if (cb >= 24) return;
    int ch = cb * 8;
    int y = p >> 7, x = p & 127;
    ushort8v o;
#pragma unroll
    for (int j = 0; j < 8; ++j) {
        int c = ch + j;
        float v = (c < 96) ? X1[c * HW + p] : X2[(c - 96) * HW + p];
        o[j] = f2b(v);
    }
    *(ushort8v*)(dst + (size_t)((y + 1) * RSB + (x + 1)) * 192 + ch) = o;
}

// ---------------------------------------------------------------------------
// conv weights -> MFMA B-fragment order, bf16:
// wB[nt][tap][kc][lane][v]: oc = nt*16+(lane&15), cin = kc*32+(lane>>4)*8+v
// ---------------------------------------------------------------------------
__global__ void prep_wB(const float* __restrict__ w, unsigned short* __restrict__ wB,
                        int CIN, int Cout, int KC) {
    int i = blockIdx.x * 256 + threadIdx.x;
    if (i >= 6 * 9 * KC * 512) return;
    int v = i & 7;
    int lane = (i >> 3) & 63;
    int t = i >> 9;
    int kc = t % KC; t /= KC;
    int tap = t % 9;
    int nt = t / 9;
    int oc = nt * 16 + (lane & 15);
    int cin = kc * 32 + (lane >> 4) * 8 + v;
    float val = (oc < Cout) ? w[(oc * CIN + cin) * 9 + tap] : 0.f;
    wB[i] = f2b(val);
}

// ---------------------------------------------------------------------------
// transpose w_d (96,32,3,3) -> wT[g][(c*9+k)*32 + (c>>3)*4 + o] (bank-staggered)
// ---------------------------------------------------------------------------
__global__ void transpose_wd(const float* __restrict__ w_d,
                             float* __restrict__ wT) {
    int i = blockIdx.x * 256 + threadIdx.x;       // 27648 total
    if (i >= 27648) return;
    int o = i & 31;
    int t = i >> 5;
    int k = t % 9; t /= 9;
    int c = t & 31;
    int g = t >> 5;
    wT[g * GSZ + ((c * 9 + k) << 5) + ((c >> 3) << 2) + o] =
        w_d[((g * 32 + o) * 32 + c) * 9 + k];
}

// ---------------------------------------------------------------------------
// 3x3 conv as 9-tap implicit GEMM via mfma_f32_16x16x32_bf16.
// Input: padded NHWC bf16, Cpad = KC*32.  Output: 96-ch bf16, either flat
// [p][96] (offset conv) or padded NHWC (feature conv).
// Block 256 = 4 waves: msub = wave&1 selects 16-px half, nh = wave>>1 selects
// 48-oc half (3 fragments).  Grid 512 (32 px per block).
// ---------------------------------------------------------------------------
template<int KC, bool FLAT_OUT>
__global__ __launch_bounds__(256) void conv_mfma(const unsigned short* __restrict__ in,
                                                 const unsigned short* __restrict__ wB,
                                                 unsigned short* __restrict__ outb) {
    const int CP = KC * 32;
    const int tid = threadIdx.x;
    const int lane = tid & 63;
    const int wid = tid >> 6;
    const int msub = wid & 1, nh = wid >> 1;
    const int pbase = blockIdx.x * 32 + msub * 16;
    const int p = pbase + (lane & 15);
    const int y = p >> 7, x = p & 127;
    const int klane = lane >> 4;
    const unsigned short* arow = in + (size_t)((y + 1) * RSB + (x + 1)) * CP + klane * 8;
    const unsigned short* wb = wB + (size_t)(nh * 3) * 9 * KC * 512 + lane * 8;

    f32x4 acc0 = {0.f, 0.f, 0.f, 0.f};
    f32x4 acc1 = {0.f, 0.f, 0.f, 0.f};
    f32x4 acc2 = {0.f, 0.f, 0.f, 0.f};

#pragma unroll
    for (int tap = 0; tap < 9; ++tap) {
        const unsigned short* at = arow + ((tap / 3 - 1) * RSB + (tap % 3 - 1)) * CP;
#pragma unroll
        for (int kc = 0; kc < KC; ++kc) {
            short8 a  = *(const short8*)(at + kc * 32);
            short8 b0 = *(const short8*)(wb + ((0 * 9 + tap) * KC + kc) * 512);
            short8 b1 = *(const short8*)(wb + ((1 * 9 + tap) * KC + kc) * 512);
            short8 b2 = *(const short8*)(wb + ((2 * 9 + tap) * KC + kc) * 512);
            acc0 = __builtin_amdgcn_mfma_f32_16x16x32_bf16(a, b0, acc0, 0, 0, 0);
            acc1 = __builtin_amdgcn_mfma_f32_16x16x32_bf16(a, b1, acc1, 0, 0, 0);
            acc2 = __builtin_amdgcn_mfma_f32_16x16x32_bf16(a, b2, acc2, 0, 0, 0);
        }
    }

    const int col = lane & 15;
#pragma unroll
    for (int r = 0; r < 4; ++r) {
        int pr = pbase + klane * 4 + r;
        int yy = pr >> 7, xx = pr & 127;
        size_t base = FLAT_OUT ? (size_t)pr * 96
                               : (size_t)((yy + 1) * RSB + (xx + 1)) * 96;
        outb[base + (nh * 3 + 0) * 16 + col] = f2b(acc0[r]);
        outb[base + (nh * 3 + 1) * 16 + col] = f2b(acc1[r]);
        outb[base + (nh * 3 + 2) * 16 + col] = f2b(acc2[r]);
    }
}

// ---------------------------------------------------------------------------
// Modulated deformable conv (DCNv2), groups=3, Cg=32, K=9.
// Feat: padded NHWC bf16.  Offsets: flat [p][96] bf16 rows.
// Block 256 = 64 px x 4 c-subsets (8 ch each); grid (256,3) XCD-swizzled.
// Per corner gather: ONE ushort8 load covers the lane's 8 channels.
// ---------------------------------------------------------------------------
__global__ __launch_bounds__(256) void dcn_kernel(const unsigned short* __restrict__ feat,
                                                  const unsigned short* __restrict__ offb,
                                                  const float* __restrict__ wT,
                                                  const float* __restrict__ b_d,
                                                  void* __restrict__ outp,
                                                  int last) {
    __shared__ float s_w[GSZ];

    const int g = blockIdx.y;
    {
        const float4* src = (const float4*)(wT + g * GSZ);
        float4* dst = (float4*)s_w;
        for (int i = threadIdx.x; i < GSZ / 4; i += 256) dst[i] = src[i];
    }
    __syncthreads();

    const int tid = threadIdx.x;
    const int csub = tid & 3;
    const int lp = tid >> 2;
    // XCD swizzle: 256 blocks = 8 xcd x 32 chunks -> contiguous 16-row bands
    const int pb = ((blockIdx.x & 7) << 5) + (blockIdx.x >> 3);
    const int p = pb * 64 + lp;
    const int y = p >> 7, x = p & 127;
    const int cbase = csub * 8;
    const unsigned short* fg = feat + g * 32 + cbase;
    const unsigned short* orow = offb + (size_t)p * 96;

    float dyv[9], dxv[9], mrv[9];
#pragma unroll
    for (int k = 0; k < 9; ++k) {
        dyv[k] = b2f(orow[g * 9 + k]);
        dxv[k] = b2f(orow[27 + g * 9 + k]);
        mrv[k] = b2f(orow[54 + g * 9 + k]);
    }

    float acc[32];
#pragma unroll
    for (int o = 0; o < 32; ++o) acc[o] = 0.f;

#pragma unroll
    for (int k = 0; k < 9; ++k) {
        float m = 1.f / (1.f + __expf(-mrv[k]));

        float py = dyv[k] + (float)y + (float)(k / 3 - 1);
        float px = dxv[k] + (float)x + (float)(k % 3 - 1);
        float y0f = floorf(py), x0f = floorf(px);
        float fy = py - y0f, fx = px - x0f;

        float vy0 = (y0f >= 0.f   && y0f <= 127.f) ? 1.f : 0.f;
        float vy1 = (y0f >= -1.f  && y0f <= 126.f) ? 1.f : 0.f;
        float vx0 = (x0f >= 0.f   && x0f <= 127.f) ? 1.f : 0.f;
        float vx1 = (x0f >= -1.f  && x0f <= 126.f) ? 1.f : 0.f;

        int iy0r = (int)y0f, ix0r = (int)x0f;
        int iy0 = min(max(iy0r, 0), 127);
        int iy1 = min(max(iy0r + 1, 0), 127);
        int ix0 = min(max(ix0r, 0), 127);
        int ix1 = min(max(ix0r + 1, 0), 127);

        float w00 = (1.f - fy) * (1.f - fx) * vy0 * vx0 * m;
        float w01 = (1.f - fy) * fx        * vy0 * vx1 * m;
        float w10 = fy        * (1.f - fx) * vy1 * vx0 * m;
        float w11 = fy        * fx         * vy1 * vx1 * m;

        int r00 = (iy0 + 1) * RSB + ix0 + 1, r01 = (iy0 + 1) * RSB + ix1 + 1;
        int r10 = (iy1 + 1) * RSB + ix0 + 1, r11 = (iy1 + 1) * RSB + ix1 + 1;
        ushort8v v00 = *(const ushort8v*)(fg + (size_t)r00 * 96);
        ushort8v v01 = *(const ushort8v*)(fg + (size_t)r01 * 96);
        ushort8v v10 = *(const ushort8v*)(fg + (size_t)r10 * 96);
        ushort8v v11 = *(const ushort8v*)(fg + (size_t)r11 * 96);

#pragma unroll
        for (int c8 = 0; c8 < 8; ++c8) {
            int c = cbase + c8;
            float v = w00 * b2f(v00[c8]) + w01 * b2f(v01[c8])
                    + w10 * b2f(v10[c8]) + w11 * b2f(v11[c8]);
            const float4* wv = (const float4*)&s_w[((c * 9 + k) << 5) + ((c >> 3) << 2)];
#pragma unroll
            for (int j = 0; j < 8; ++j) {
                float4 ww = wv[j];
                acc[4 * j + 0] += v * ww.x;
                acc[4 * j + 1] += v * ww.y;
                acc[4 * j + 2] += v * ww.z;
                acc[4 * j + 3] += v * ww.w;
            }
        }
    }

    // reduce c-split across the 4 csub lanes (same pixel)
#pragma unroll
    for (int o = 0; o < 32; ++o) {
        acc[o] += __shfl_xor(acc[o], 1);
        acc[o] += __shfl_xor(acc[o], 2);
    }

    if (!last) {
        unsigned short* fo = (unsigned short*)outp;
        ushort8v o;
#pragma unroll
        for (int j = 0; j < 8; ++j) {
            float vj = (csub == 0) ? acc[j]
                     : (csub == 1) ? acc[8 + j]
                     : (csub == 2) ? acc[16 + j]
                     :               acc[24 + j];
            o[j] = f2b(vj + b_d[g * 32 + cbase + j]);
        }
        *(ushort8v*)(fo + (size_t)((y + 1) * RSB + (x + 1)) * 96 + g * 32 + cbase) = o;
    } else {
        float* fo = (float*)outp;
#pragma unroll
        for (int j = 0; j < 8; ++j) {
            float vj = (csub == 0) ? acc[j]
                     : (csub == 1) ? acc[8 + j]
                     : (csub == 2) ? acc[16 + j]
                     :               acc[24 + j];
            int ch = g * 32 + cbase + j;
            fo[(size_t)ch * HW + p] = vj + b_d[ch];
        }
    }
}

// ---------------------------------------------------------------------------
extern "C" void kernel_launch(void* const* d_in, const int* in_sizes, int n_in,
                              void* d_out, int out_size, void* d_ws, size_t ws_size,
                              hipStream_t stream) {
    const float* X1    = (const float*)d_in[0];
    const float* X2    = (const float*)d_in[1];
    const float* w_bot = (const float*)d_in[2];
    const float* w_off[4] = {(const float*)d_in[3], (const float*)d_in[6],
                             (const float*)d_in[9], (const float*)d_in[12]};
    const float* w_d[4]   = {(const float*)d_in[4], (const float*)d_in[7],
                             (const float*)d_in[10], (const float*)d_in[13]};
    const float* b_d[4]   = {(const float*)d_in[5], (const float*)d_in[8],
                             (const float*)d_in[11], (const float*)d_in[14]};

    // workspace layout (ushort units unless noted):
    unsigned short* in_nhwc = (unsigned short*)d_ws;          // 130*130*192 = 3,244,800
    unsigned short* featA   = in_nhwc + 3244800;              // 130*130*96  = 1,622,400
    unsigned short* featB   = featA + 1622400;                // 1,622,400
    unsigned short* off_b   = featB + 1622400;                // 16384*96    = 1,572,864
    unsigned short* wBbot   = off_b + 1572864;                // 165,888
    unsigned short* wBoff   = wBbot + 165888;                 // 82,944
    float*          wTd     = (float*)(wBoff + 82944);        // 27,792 floats
    // total = 16.73 MB

    // zero padded buffers (borders must be 0; interiors overwritten every call)
    hipMemsetAsync(in_nhwc, 0, (size_t)(3244800 + 2 * 1622400) * 2, stream);

    pack_nhwc<<<1536, 256, 0, stream>>>(X1, X2, in_nhwc);
    prep_wB<<<648, 256, 0, stream>>>(w_bot, wBbot, 192, 96, 6);
    conv_mfma<6, false><<<512, 256, 0, stream>>>(in_nhwc, wBbot, featA);

    unsigned short* cur = featA;
    unsigned short* nxt = featB;
    for (int it = 0; it < 4; ++it) {
        prep_wB<<<324, 256, 0, stream>>>(w_off[it], wBoff, 96, 81, 3);
        conv_mfma<3, true><<<512, 256, 0, stream>>>(cur, wBoff, off_b);
        transpose_wd<<<108, 256, 0, stream>>>(w_d[it], wTd);
        void* outp = (it == 3) ? d_out : (void*)nxt;
        dcn_kernel<<<dim3(256, 3), 256, 0, stream>>>(cur, off_b, wTd, b_d[it],
                                                     outp, it == 3 ? 1 : 0);
        unsigned short* t = cur; cur = nxt; nxt = t;
    }
}

// Round 9
// 144.039 us; speedup vs baseline: 9.9675x; 1.4336x over previous
//
#include <hip/hip_runtime.h>

#define HW 16384   // 128*128
#define W_ 128
#define RSB 130    // padded row stride (pixels)

typedef short short8 __attribute__((ext_vector_type(8)));
typedef float f32x4 __attribute__((ext_vector_type(4)));
typedef unsigned short ushort8v __attribute__((ext_vector_type(8)));

__device__ __forceinline__ float b2f(unsigned short u) {
    return __uint_as_float(((unsigned)u) << 16);
}
__device__ __forceinline__ unsigned short f2b(float f) {
    unsigned u = __float_as_uint(f);
    return (unsigned short)((u + 0x7fffu + ((u >> 16) & 1u)) >> 16);
}

// ---------------------------------------------------------------------------
// pack cat(X1[0], X2[0]) -> padded NHWC bf16 (192 ch); borders zeroed by prep
// ---------------------------------------------------------------------------
__global__ __launch_bounds__(256) void pack_nhwc(const float* __restrict__ X1,
                                                 const float* __restrict__ X2,
                                                 unsigned short* __restrict__ dst) {
    int i = blockIdx.x * 256 + threadIdx.x;      // 16384*24
    int p = i & (HW - 1);
    int cb = i >> 14;
    if (cb >= 24) return;
    int ch = cb * 8;
    int y = p >> 7, x = p & 127;
    ushort8v o;
#pragma unroll
    for (int j = 0; j < 8; ++j) {
        int c = ch + j;
        float v = (c < 96) ? X1[c * HW + p] : X2[(c - 96) * HW + p];
        o[j] = f2b(v);
    }
    *(ushort8v*)(dst + (size_t)((y + 1) * RSB + (x + 1)) * 192 + ch) = o;
}

// ---------------------------------------------------------------------------
// One-shot prep: all conv/dcn weight B-fragments (bf16) + border zeroing.
// grid (648, 10): region 0 = bot wB; 1-4 = off wB per layer; 5-8 = dcn wB
// per layer; 9 = zero borders of in_nhwc/featA/featB.
// B-fragment order i = (((nt*9+tap)*KC+kc)*64+lane)*8+v;
//   oc = nt*16+(lane&15), cin = kc*32+(lane>>4)*8+v  (verified by r8 pass).
// dcn: i = ((((g*9+tap)*2+nt)*64)+lane)*8+v; oc = nt*16+(lane&15), c=(lane>>4)*8+v.
// ---------------------------------------------------------------------------
__global__ __launch_bounds__(256) void prep_all(
    const float* __restrict__ w_bot,
    const float* __restrict__ w_off0, const float* __restrict__ w_off1,
    const float* __restrict__ w_off2, const float* __restrict__ w_off3,
    const float* __restrict__ w_d0, const float* __restrict__ w_d1,
    const float* __restrict__ w_d2, const float* __restrict__ w_d3,
    unsigned short* __restrict__ wBbot, unsigned short* __restrict__ wBoff,
    unsigned short* __restrict__ wdB,  unsigned short* __restrict__ in_nhwc,
    unsigned short* __restrict__ featA, unsigned short* __restrict__ featB) {
    const int region = blockIdx.y;
    const int i = blockIdx.x * 256 + threadIdx.x;
    if (region == 0) {
        if (i >= 165888) return;                  // KC=6, CIN=192, Cout=96
        int v = i & 7, lane = (i >> 3) & 63, t = i >> 9;
        int kc = t % 6; t /= 6;
        int tap = t % 9, nt = t / 9;
        int oc = nt * 16 + (lane & 15), cin = kc * 32 + (lane >> 4) * 8 + v;
        wBbot[i] = f2b(oc < 96 ? w_bot[(oc * 192 + cin) * 9 + tap] : 0.f);
    } else if (region <= 4) {
        if (i >= 82944) return;                   // KC=3, CIN=96, Cout=81
        const float* w = region == 1 ? w_off0 : region == 2 ? w_off1
                       : region == 3 ? w_off2 : w_off3;
        int v = i & 7, lane = (i >> 3) & 63, t = i >> 9;
        int kc = t % 3; t /= 3;
        int tap = t % 9, nt = t / 9;
        int oc = nt * 16 + (lane & 15), cin = kc * 32 + (lane >> 4) * 8 + v;
        wBoff[(region - 1) * 82944 + i] = f2b(oc < 81 ? w[(oc * 96 + cin) * 9 + tap] : 0.f);
    } else if (region <= 8) {
        if (i >= 27648) return;                   // dcn grouped weights
        const float* w = region == 5 ? w_d0 : region == 6 ? w_d1
                       : region == 7 ? w_d2 : w_d3;
        int v = i & 7, lane = (i >> 3) & 63, t = i >> 9;
        int nt = t & 1; t >>= 1;
        int tap = t % 9, g = t / 9;
        int oc = nt * 16 + (lane & 15), c = (lane >> 4) * 8 + v;
        wdB[(region - 5) * 27648 + i] = f2b(w[((g * 32 + oc) * 32 + c) * 9 + tap]);
    } else {
        if (i >= 516 * 48) return;                // border zeroing (ushort8)
        int bp = i / 48, c8 = i % 48;
        int y, x;
        if (bp < 130)      { y = 0;   x = bp; }
        else if (bp < 260) { y = 129; x = bp - 130; }
        else { int t2 = bp - 260; y = 1 + (t2 >> 1); x = (t2 & 1) ? 129 : 0; }
        size_t pix = (size_t)y * RSB + x;
        ushort8v z = {0, 0, 0, 0, 0, 0, 0, 0};
        if (c8 < 24)      *(ushort8v*)(in_nhwc + pix * 192 + c8 * 8) = z;
        else if (c8 < 36) *(ushort8v*)(featA + pix * 96 + (c8 - 24) * 8) = z;
        else              *(ushort8v*)(featB + pix * 96 + (c8 - 36) * 8) = z;
    }
}

// ---------------------------------------------------------------------------
// 3x3 conv as 9-tap implicit GEMM via mfma_f32_16x16x32_bf16.  (r8-proven)
// ---------------------------------------------------------------------------
template<int KC, bool FLAT_OUT>
__global__ __launch_bounds__(256) void conv_mfma(const unsigned short* __restrict__ in,
                                                 const unsigned short* __restrict__ wB,
                                                 unsigned short* __restrict__ outb) {
    const int CP = KC * 32;
    const int tid = threadIdx.x;
    const int lane = tid & 63;
    const int wid = tid >> 6;
    const int msub = wid & 1, nh = wid >> 1;
    const int pbase = blockIdx.x * 32 + msub * 16;
    const int p = pbase + (lane & 15);
    const int y = p >> 7, x = p & 127;
    const int klane = lane >> 4;
    const unsigned short* arow = in + (size_t)((y + 1) * RSB + (x + 1)) * CP + klane * 8;
    const unsigned short* wb = wB + (size_t)(nh * 3) * 9 * KC * 512 + lane * 8;

    f32x4 acc0 = {0.f, 0.f, 0.f, 0.f};
    f32x4 acc1 = {0.f, 0.f, 0.f, 0.f};
    f32x4 acc2 = {0.f, 0.f, 0.f, 0.f};

#pragma unroll
    for (int tap = 0; tap < 9; ++tap) {
        const unsigned short* at = arow + ((tap / 3 - 1) * RSB + (tap % 3 - 1)) * CP;
#pragma unroll
        for (int kc = 0; kc < KC; ++kc) {
            short8 a  = *(const short8*)(at + kc * 32);
            short8 b0 = *(const short8*)(wb + ((0 * 9 + tap) * KC + kc) * 512);
            short8 b1 = *(const short8*)(wb + ((1 * 9 + tap) * KC + kc) * 512);
            short8 b2 = *(const short8*)(wb + ((2 * 9 + tap) * KC + kc) * 512);
            acc0 = __builtin_amdgcn_mfma_f32_16x16x32_bf16(a, b0, acc0, 0, 0, 0);
            acc1 = __builtin_amdgcn_mfma_f32_16x16x32_bf16(a, b1, acc1, 0, 0, 0);
            acc2 = __builtin_amdgcn_mfma_f32_16x16x32_bf16(a, b2, acc2, 0, 0, 0);
        }
    }

    const int col = lane & 15;
#pragma unroll
    for (int r = 0; r < 4; ++r) {
        int pr = pbase + klane * 4 + r;
        int yy = pr >> 7, xx = pr & 127;
        size_t base = FLAT_OUT ? (size_t)pr * 96
                               : (size_t)((yy + 1) * RSB + (xx + 1)) * 96;
        outb[base + (nh * 3 + 0) * 16 + col] = f2b(acc0[r]);
        outb[base + (nh * 3 + 1) * 16 + col] = f2b(acc1[r]);
        outb[base + (nh * 3 + 2) * 16 + col] = f2b(acc2[r]);
    }
}

// ---------------------------------------------------------------------------
// Modulated deformable conv (DCNv2) with MFMA einsum.
// Wave = 16 px x 4 channel-octets: each lane's 8 bilinear vals per tap ARE
// the A-fragment k-slice (row=lane&15=pixel, k=(lane>>4)*8+v=channel).
// Per tap: 2 MFMAs (oc 0-15 / 16-31).  Grid (256,3) XCD-swizzled.
// ---------------------------------------------------------------------------
__global__ __launch_bounds__(256) void dcn_kernel(const unsigned short* __restrict__ feat,
                                                  const unsigned short* __restrict__ offb,
                                                  const unsigned short* __restrict__ wdB,
                                                  const float* __restrict__ b_d,
                                                  void* __restrict__ outp,
                                                  int last) {
    const int tid = threadIdx.x;
    const int lane = tid & 63;
    const int wv = tid >> 6;
    const int g = blockIdx.y;
    // XCD swizzle: 256 blocks = 8 xcd x 32 chunks -> contiguous 16-row bands
    const int pb = ((blockIdx.x & 7) << 5) + (blockIdx.x >> 3);
    const int pbase = pb * 64 + wv * 16;
    const int col = lane & 15, klane = lane >> 4;
    const int p = pbase + col;
    const int y = p >> 7, x = p & 127;
    const int coct = klane * 8;

    const unsigned short* orow = offb + (size_t)p * 96 + g * 9;
    float dyv[9], dxv[9], mrv[9];
#pragma unroll
    for (int k = 0; k < 9; ++k) {
        dyv[k] = b2f(orow[k]);
        dxv[k] = b2f(orow[27 + k]);
        mrv[k] = b2f(orow[54 + k]);
    }

    const unsigned short* fgc = feat + g * 32 + coct;
    const unsigned short* wb = wdB + (size_t)g * 9 * 2 * 512 + lane * 8;

    f32x4 acc0 = {0.f, 0.f, 0.f, 0.f};
    f32x4 acc1 = {0.f, 0.f, 0.f, 0.f};

#pragma unroll
    for (int k = 0; k < 9; ++k) {
        float m = 1.f / (1.f + __expf(-mrv[k]));

        float py = dyv[k] + (float)y + (float)(k / 3 - 1);
        float px = dxv[k] + (float)x + (float)(k % 3 - 1);
        float y0f = floorf(py), x0f = floorf(px);
        float fy = py - y0f, fx = px - x0f;

        float vy0 = (y0f >= 0.f   && y0f <= 127.f) ? 1.f : 0.f;
        float vy1 = (y0f >= -1.f  && y0f <= 126.f) ? 1.f : 0.f;
        float vx0 = (x0f >= 0.f   && x0f <= 127.f) ? 1.f : 0.f;
        float vx1 = (x0f >= -1.f  && x0f <= 126.f) ? 1.f : 0.f;

        int iy0r = (int)y0f, ix0r = (int)x0f;
        int iy0 = min(max(iy0r, 0), 127);
        int iy1 = min(max(iy0r + 1, 0), 127);
        int ix0 = min(max(ix0r, 0), 127);
        int ix1 = min(max(ix0r + 1, 0), 127);

        float w00 = (1.f - fy) * (1.f - fx) * vy0 * vx0 * m;
        float w01 = (1.f - fy) * fx        * vy0 * vx1 * m;
        float w10 = fy        * (1.f - fx) * vy1 * vx0 * m;
        float w11 = fy        * fx         * vy1 * vx1 * m;

        int r00 = (iy0 + 1) * RSB + ix0 + 1, r01 = (iy0 + 1) * RSB + ix1 + 1;
        int r10 = (iy1 + 1) * RSB + ix0 + 1, r11 = (iy1 + 1) * RSB + ix1 + 1;
        ushort8v v00 = *(const ushort8v*)(fgc + (size_t)r00 * 96);
        ushort8v v01 = *(const ushort8v*)(fgc + (size_t)r01 * 96);
        ushort8v v10 = *(const ushort8v*)(fgc + (size_t)r10 * 96);
        ushort8v v11 = *(const ushort8v*)(fgc + (size_t)r11 * 96);

        short8 a;
#pragma unroll
        for (int j = 0; j < 8; ++j) {
            float val = w00 * b2f(v00[j]) + w01 * b2f(v01[j])
                      + w10 * b2f(v10[j]) + w11 * b2f(v11[j]);
            a[j] = (short)f2b(val);
        }
        short8 b0 = *(const short8*)(wb + (k * 2 + 0) * 512);
        short8 b1 = *(const short8*)(wb + (k * 2 + 1) * 512);
        acc0 = __builtin_amdgcn_mfma_f32_16x16x32_bf16(a, b0, acc0, 0, 0, 0);
        acc1 = __builtin_amdgcn_mfma_f32_16x16x32_bf16(a, b1, acc1, 0, 0, 0);
    }

#pragma unroll
    for (int r = 0; r < 4; ++r) {
        int pr = pbase + klane * 4 + r;
        int ch0 = g * 32 + col, ch1 = g * 32 + 16 + col;
        float o0 = acc0[r] + b_d[ch0];
        float o1 = acc1[r] + b_d[ch1];
        if (!last) {
            int yy = pr >> 7, xx = pr & 127;
            unsigned short* fo = (unsigned short*)outp;
            size_t base = (size_t)((yy + 1) * RSB + (xx + 1)) * 96;
            fo[base + ch0] = f2b(o0);
            fo[base + ch1] = f2b(o1);
        } else {
            float* fo = (float*)outp;
            fo[(size_t)ch0 * HW + pr] = o0;
            fo[(size_t)ch1 * HW + pr] = o1;
        }
    }
}

// ---------------------------------------------------------------------------
extern "C" void kernel_launch(void* const* d_in, const int* in_sizes, int n_in,
                              void* d_out, int out_size, void* d_ws, size_t ws_size,
                              hipStream_t stream) {
    const float* X1    = (const float*)d_in[0];
    const float* X2    = (const float*)d_in[1];
    const float* w_bot = (const float*)d_in[2];
    const float* w_off[4] = {(const float*)d_in[3], (const float*)d_in[6],
                             (const float*)d_in[9], (const float*)d_in[12]};
    const float* w_d[4]   = {(const float*)d_in[4], (const float*)d_in[7],
                             (const float*)d_in[10], (const float*)d_in[13]};
    const float* b_d[4]   = {(const float*)d_in[5], (const float*)d_in[8],
                             (const float*)d_in[11], (const float*)d_in[14]};

    // workspace layout (ushort units):
    unsigned short* in_nhwc = (unsigned short*)d_ws;          // 130*130*192 = 3,244,800
    unsigned short* featA   = in_nhwc + 3244800;              // 130*130*96  = 1,622,400
    unsigned short* featB   = featA + 1622400;                // 1,622,400
    unsigned short* off_b   = featB + 1622400;                // 16384*96    = 1,572,864
    unsigned short* wBbot   = off_b + 1572864;                // 165,888
    unsigned short* wBoff   = wBbot + 165888;                 // 4 x 82,944
    unsigned short* wdB     = wBoff + 4 * 82944;              // 4 x 27,648
    // total 8,670,720 ushorts = 17.34 MB

    prep_all<<<dim3(648, 10), 256, 0, stream>>>(
        w_bot, w_off[0], w_off[1], w_off[2], w_off[3],
        w_d[0], w_d[1], w_d[2], w_d[3],
        wBbot, wBoff, wdB, in_nhwc, featA, featB);
    pack_nhwc<<<1536, 256, 0, stream>>>(X1, X2, in_nhwc);
    conv_mfma<6, false><<<512, 256, 0, stream>>>(in_nhwc, wBbot, featA);

    unsigned short* cur = featA;
    unsigned short* nxt = featB;
    for (int it = 0; it < 4; ++it) {
        conv_mfma<3, true><<<512, 256, 0, stream>>>(cur, wBoff + it * 82944, off_b);
        void* outp = (it == 3) ? d_out : (void*)nxt;
        dcn_kernel<<<dim3(256, 3), 256, 0, stream>>>(cur, off_b, wdB + it * 27648,
                                                     b_d[it], outp, it == 3 ? 1 : 0);
        unsigned short* t = cur; cur = nxt; nxt = t;
    }
}

// Round 10
// 122.904 us; speedup vs baseline: 11.6816x; 1.1720x over previous
//
#include <hip/hip_runtime.h>

#define HW 16384   // 128*128
#define W_ 128
#define RSB 130    // padded row stride (pixels)

typedef short short8 __attribute__((ext_vector_type(8)));
typedef float f32x4 __attribute__((ext_vector_type(4)));
typedef unsigned short ushort8v __attribute__((ext_vector_type(8)));

__device__ __forceinline__ float b2f(unsigned short u) {
    return __uint_as_float(((unsigned)u) << 16);
}
__device__ __forceinline__ unsigned short f2b(float f) {
    unsigned u = __float_as_uint(f);
    return (unsigned short)((u + 0x7fffu + ((u >> 16) & 1u)) >> 16);
}

// ---------------------------------------------------------------------------
// pack cat(X1[0], X2[0]) -> padded NHWC bf16 (192 ch); borders zeroed by prep
// ---------------------------------------------------------------------------
__global__ __launch_bounds__(256) void pack_nhwc(const float* __restrict__ X1,
                                                 const float* __restrict__ X2,
                                                 unsigned short* __restrict__ dst) {
    int i = blockIdx.x * 256 + threadIdx.x;      // 16384*24
    int p = i & (HW - 1);
    int cb = i >> 14;
    if (cb >= 24) return;
    int ch = cb * 8;
    int y = p >> 7, x = p & 127;
    ushort8v o;
#pragma unroll
    for (int j = 0; j < 8; ++j) {
        int c = ch + j;
        float v = (c < 96) ? X1[c * HW + p] : X2[(c - 96) * HW + p];
        o[j] = f2b(v);
    }
    *(ushort8v*)(dst + (size_t)((y + 1) * RSB + (x + 1)) * 192 + ch) = o;
}

// ---------------------------------------------------------------------------
// One-shot prep: all conv/dcn weight B-fragments (bf16) + border zeroing.
// grid (648, 10).  Fragment orders verified by r8/r9 passing runs.
// ---------------------------------------------------------------------------
__global__ __launch_bounds__(256) void prep_all(
    const float* __restrict__ w_bot,
    const float* __restrict__ w_off0, const float* __restrict__ w_off1,
    const float* __restrict__ w_off2, const float* __restrict__ w_off3,
    const float* __restrict__ w_d0, const float* __restrict__ w_d1,
    const float* __restrict__ w_d2, const float* __restrict__ w_d3,
    unsigned short* __restrict__ wBbot, unsigned short* __restrict__ wBoff,
    unsigned short* __restrict__ wdB,  unsigned short* __restrict__ in_nhwc,
    unsigned short* __restrict__ featA, unsigned short* __restrict__ featB) {
    const int region = blockIdx.y;
    const int i = blockIdx.x * 256 + threadIdx.x;
    if (region == 0) {
        if (i >= 165888) return;                  // KC=6, CIN=192, Cout=96
        int v = i & 7, lane = (i >> 3) & 63, t = i >> 9;
        int kc = t % 6; t /= 6;
        int tap = t % 9, nt = t / 9;
        int oc = nt * 16 + (lane & 15), cin = kc * 32 + (lane >> 4) * 8 + v;
        wBbot[i] = f2b(oc < 96 ? w_bot[(oc * 192 + cin) * 9 + tap] : 0.f);
    } else if (region <= 4) {
        if (i >= 82944) return;                   // KC=3, CIN=96, Cout=81
        const float* w = region == 1 ? w_off0 : region == 2 ? w_off1
                       : region == 3 ? w_off2 : w_off3;
        int v = i & 7, lane = (i >> 3) & 63, t = i >> 9;
        int kc = t % 3; t /= 3;
        int tap = t % 9, nt = t / 9;
        int oc = nt * 16 + (lane & 15), cin = kc * 32 + (lane >> 4) * 8 + v;
        wBoff[(region - 1) * 82944 + i] = f2b(oc < 81 ? w[(oc * 96 + cin) * 9 + tap] : 0.f);
    } else if (region <= 8) {
        if (i >= 27648) return;                   // dcn grouped weights
        const float* w = region == 5 ? w_d0 : region == 6 ? w_d1
                       : region == 7 ? w_d2 : w_d3;
        int v = i & 7, lane = (i >> 3) & 63, t = i >> 9;
        int nt = t & 1; t >>= 1;
        int tap = t % 9, g = t / 9;
        int oc = nt * 16 + (lane & 15), c = (lane >> 4) * 8 + v;
        wdB[(region - 5) * 27648 + i] = f2b(w[((g * 32 + oc) * 32 + c) * 9 + tap]);
    } else {
        if (i >= 516 * 48) return;                // border zeroing (ushort8)
        int bp = i / 48, c8 = i % 48;
        int y, x;
        if (bp < 130)      { y = 0;   x = bp; }
        else if (bp < 260) { y = 129; x = bp - 130; }
        else { int t2 = bp - 260; y = 1 + (t2 >> 1); x = (t2 & 1) ? 129 : 0; }
        size_t pix = (size_t)y * RSB + x;
        ushort8v z = {0, 0, 0, 0, 0, 0, 0, 0};
        if (c8 < 24)      *(ushort8v*)(in_nhwc + pix * 192 + c8 * 8) = z;
        else if (c8 < 36) *(ushort8v*)(featA + pix * 96 + (c8 - 24) * 8) = z;
        else              *(ushort8v*)(featB + pix * 96 + (c8 - 36) * 8) = z;
    }
}

// ---------------------------------------------------------------------------
// 3x3 conv as 9-tap implicit GEMM via mfma_f32_16x16x32_bf16.  (r8-proven)
// Used for the bottom conv only (192 -> 96, padded NHWC out).
// ---------------------------------------------------------------------------
template<int KC, bool FLAT_OUT>
__global__ __launch_bounds__(256) void conv_mfma(const unsigned short* __restrict__ in,
                                                 const unsigned short* __restrict__ wB,
                                                 unsigned short* __restrict__ outb) {
    const int CP = KC * 32;
    const int tid = threadIdx.x;
    const int lane = tid & 63;
    const int wid = tid >> 6;
    const int msub = wid & 1, nh = wid >> 1;
    const int pbase = blockIdx.x * 32 + msub * 16;
    const int p = pbase + (lane & 15);
    const int y = p >> 7, x = p & 127;
    const int klane = lane >> 4;
    const unsigned short* arow = in + (size_t)((y + 1) * RSB + (x + 1)) * CP + klane * 8;
    const unsigned short* wb = wB + (size_t)(nh * 3) * 9 * KC * 512 + lane * 8;

    f32x4 acc0 = {0.f, 0.f, 0.f, 0.f};
    f32x4 acc1 = {0.f, 0.f, 0.f, 0.f};
    f32x4 acc2 = {0.f, 0.f, 0.f, 0.f};

#pragma unroll
    for (int tap = 0; tap < 9; ++tap) {
        const unsigned short* at = arow + ((tap / 3 - 1) * RSB + (tap % 3 - 1)) * CP;
#pragma unroll
        for (int kc = 0; kc < KC; ++kc) {
            short8 a  = *(const short8*)(at + kc * 32);
            short8 b0 = *(const short8*)(wb + ((0 * 9 + tap) * KC + kc) * 512);
            short8 b1 = *(const short8*)(wb + ((1 * 9 + tap) * KC + kc) * 512);
            short8 b2 = *(const short8*)(wb + ((2 * 9 + tap) * KC + kc) * 512);
            acc0 = __builtin_amdgcn_mfma_f32_16x16x32_bf16(a, b0, acc0, 0, 0, 0);
            acc1 = __builtin_amdgcn_mfma_f32_16x16x32_bf16(a, b1, acc1, 0, 0, 0);
            acc2 = __builtin_amdgcn_mfma_f32_16x16x32_bf16(a, b2, acc2, 0, 0, 0);
        }
    }

    const int col = lane & 15;
#pragma unroll
    for (int r = 0; r < 4; ++r) {
        int pr = pbase + klane * 4 + r;
        int yy = pr >> 7, xx = pr & 127;
        size_t base = FLAT_OUT ? (size_t)pr * 96
                               : (size_t)((yy + 1) * RSB + (xx + 1)) * 96;
        outb[base + (nh * 3 + 0) * 16 + col] = f2b(acc0[r]);
        outb[base + (nh * 3 + 1) * 16 + col] = f2b(acc1[r]);
        outb[base + (nh * 3 + 2) * 16 + col] = f2b(acc2[r]);
    }
}

// ---------------------------------------------------------------------------
// FUSED offset-conv + DCN per layer.  Block = 512 thr (8 waves) = 64 pixels.
// Phase A: offset conv (8 subtasks of 16px x 48oc MFMA) -> raw f32 offsets
// in LDS s_off[64][97] (pad 97: phase-B reads hit 16 distinct banks).
// Phase B: DCN (12 subtasks of 16px x group; waves 0-3 take two).
// Grid 256, XCD-swizzled to contiguous 16-row bands for gather L2 locality.
// ---------------------------------------------------------------------------
__global__ __launch_bounds__(512) void offdcn_kernel(
    const unsigned short* __restrict__ feat,   // cur layer feat, padded NHWC 96
    const unsigned short* __restrict__ wBoff,  // this layer's offset-conv B-frags
    const unsigned short* __restrict__ wdB,    // this layer's dcn B-frags
    const float* __restrict__ b_d,
    void* __restrict__ outp, int last) {
    __shared__ float s_off[64][97];

    const int tid = threadIdx.x;
    const int lane = tid & 63;
    const int w = tid >> 6;                       // wave 0..7
    const int col = lane & 15, klane = lane >> 4;
    const int pb = ((blockIdx.x & 7) << 5) + (blockIdx.x >> 3);
    const int P0 = pb * 64;

    // ---------------- phase A: offset conv ----------------
    {
        const int pf = w >> 1, nh = w & 1;
        const int p = P0 + pf * 16 + col;
        const int y = p >> 7, x = p & 127;
        const unsigned short* arow = feat + (size_t)((y + 1) * RSB + (x + 1)) * 96 + klane * 8;
        const unsigned short* wb = wBoff + (size_t)(nh * 3) * 9 * 3 * 512 + lane * 8;

        f32x4 a0 = {0.f, 0.f, 0.f, 0.f};
        f32x4 a1 = {0.f, 0.f, 0.f, 0.f};
        f32x4 a2 = {0.f, 0.f, 0.f, 0.f};
#pragma unroll
        for (int tap = 0; tap < 9; ++tap) {
            const unsigned short* at = arow + ((tap / 3 - 1) * RSB + (tap % 3 - 1)) * 96;
#pragma unroll
            for (int kc = 0; kc < 3; ++kc) {
                short8 a  = *(const short8*)(at + kc * 32);
                short8 b0 = *(const short8*)(wb + ((0 * 9 + tap) * 3 + kc) * 512);
                short8 b1 = *(const short8*)(wb + ((1 * 9 + tap) * 3 + kc) * 512);
                short8 b2 = *(const short8*)(wb + ((2 * 9 + tap) * 3 + kc) * 512);
                a0 = __builtin_amdgcn_mfma_f32_16x16x32_bf16(a, b0, a0, 0, 0, 0);
                a1 = __builtin_amdgcn_mfma_f32_16x16x32_bf16(a, b1, a1, 0, 0, 0);
                a2 = __builtin_amdgcn_mfma_f32_16x16x32_bf16(a, b2, a2, 0, 0, 0);
            }
        }
#pragma unroll
        for (int r = 0; r < 4; ++r) {
            int pl = pf * 16 + klane * 4 + r;
            s_off[pl][nh * 48 + 0 * 16 + col] = a0[r];
            s_off[pl][nh * 48 + 1 * 16 + col] = a1[r];
            s_off[pl][nh * 48 + 2 * 16 + col] = a2[r];
        }
    }
    __syncthreads();

    // ---------------- phase B: DCN ----------------
    for (int sidx = w; sidx < 12; sidx += 8) {
        const int pf = sidx & 3, g = sidx >> 2;
        const int p = P0 + pf * 16 + col;
        const int y = p >> 7, x = p & 127;
        const int pl = pf * 16 + col;
        const int coct = klane * 8;

        float dyv[9], dxv[9], mrv[9];
#pragma unroll
        for (int k = 0; k < 9; ++k) {
            dyv[k] = s_off[pl][g * 9 + k];
            dxv[k] = s_off[pl][27 + g * 9 + k];
            mrv[k] = s_off[pl][54 + g * 9 + k];
        }

        const unsigned short* fgc = feat + g * 32 + coct;
        const unsigned short* wb = wdB + (size_t)g * 9 * 2 * 512 + lane * 8;

        f32x4 acc0 = {0.f, 0.f, 0.f, 0.f};
        f32x4 acc1 = {0.f, 0.f, 0.f, 0.f};

#pragma unroll
        for (int k = 0; k < 9; ++k) {
            float m = 1.f / (1.f + __expf(-mrv[k]));

            float py = dyv[k] + (float)y + (float)(k / 3 - 1);
            float px = dxv[k] + (float)x + (float)(k % 3 - 1);
            float y0f = floorf(py), x0f = floorf(px);
            float fy = py - y0f, fx = px - x0f;

            float vy0 = (y0f >= 0.f   && y0f <= 127.f) ? 1.f : 0.f;
            float vy1 = (y0f >= -1.f  && y0f <= 126.f) ? 1.f : 0.f;
            float vx0 = (x0f >= 0.f   && x0f <= 127.f) ? 1.f : 0.f;
            float vx1 = (x0f >= -1.f  && x0f <= 126.f) ? 1.f : 0.f;

            int iy0r = (int)y0f, ix0r = (int)x0f;
            int iy0 = min(max(iy0r, 0), 127);
            int iy1 = min(max(iy0r + 1, 0), 127);
            int ix0 = min(max(ix0r, 0), 127);
            int ix1 = min(max(ix0r + 1, 0), 127);

            float w00 = (1.f - fy) * (1.f - fx) * vy0 * vx0 * m;
            float w01 = (1.f - fy) * fx        * vy0 * vx1 * m;
            float w10 = fy        * (1.f - fx) * vy1 * vx0 * m;
            float w11 = fy        * fx         * vy1 * vx1 * m;

            int r00 = (iy0 + 1) * RSB + ix0 + 1, r01 = (iy0 + 1) * RSB + ix1 + 1;
            int r10 = (iy1 + 1) * RSB + ix0 + 1, r11 = (iy1 + 1) * RSB + ix1 + 1;
            ushort8v v00 = *(const ushort8v*)(fgc + (size_t)r00 * 96);
            ushort8v v01 = *(const ushort8v*)(fgc + (size_t)r01 * 96);
            ushort8v v10 = *(const ushort8v*)(fgc + (size_t)r10 * 96);
            ushort8v v11 = *(const ushort8v*)(fgc + (size_t)r11 * 96);

            short8 a;
#pragma unroll
            for (int j = 0; j < 8; ++j) {
                float val = w00 * b2f(v00[j]) + w01 * b2f(v01[j])
                          + w10 * b2f(v10[j]) + w11 * b2f(v11[j]);
                a[j] = (short)f2b(val);
            }
            short8 b0 = *(const short8*)(wb + (k * 2 + 0) * 512);
            short8 b1 = *(const short8*)(wb + (k * 2 + 1) * 512);
            acc0 = __builtin_amdgcn_mfma_f32_16x16x32_bf16(a, b0, acc0, 0, 0, 0);
            acc1 = __builtin_amdgcn_mfma_f32_16x16x32_bf16(a, b1, acc1, 0, 0, 0);
        }

#pragma unroll
        for (int r = 0; r < 4; ++r) {
            int pr = P0 + pf * 16 + klane * 4 + r;
            int ch0 = g * 32 + col, ch1 = g * 32 + 16 + col;
            float o0 = acc0[r] + b_d[ch0];
            float o1 = acc1[r] + b_d[ch1];
            if (!last) {
                int yy = pr >> 7, xx = pr & 127;
                unsigned short* fo = (unsigned short*)outp;
                size_t base = (size_t)((yy + 1) * RSB + (xx + 1)) * 96;
                fo[base + ch0] = f2b(o0);
                fo[base + ch1] = f2b(o1);
            } else {
                float* fo = (float*)outp;
                fo[(size_t)ch0 * HW + pr] = o0;
                fo[(size_t)ch1 * HW + pr] = o1;
            }
        }
    }
}

// ---------------------------------------------------------------------------
extern "C" void kernel_launch(void* const* d_in, const int* in_sizes, int n_in,
                              void* d_out, int out_size, void* d_ws, size_t ws_size,
                              hipStream_t stream) {
    const float* X1    = (const float*)d_in[0];
    const float* X2    = (const float*)d_in[1];
    const float* w_bot = (const float*)d_in[2];
    const float* w_off[4] = {(const float*)d_in[3], (const float*)d_in[6],
                             (const float*)d_in[9], (const float*)d_in[12]};
    const float* w_d[4]   = {(const float*)d_in[4], (const float*)d_in[7],
                             (const float*)d_in[10], (const float*)d_in[13]};
    const float* b_d[4]   = {(const float*)d_in[5], (const float*)d_in[8],
                             (const float*)d_in[11], (const float*)d_in[14]};

    // workspace layout (ushort units):
    unsigned short* in_nhwc = (unsigned short*)d_ws;          // 130*130*192 = 3,244,800
    unsigned short* featA   = in_nhwc + 3244800;              // 130*130*96  = 1,622,400
    unsigned short* featB   = featA + 1622400;                // 1,622,400
    unsigned short* wBbot   = featB + 1622400;                // 165,888
    unsigned short* wBoff   = wBbot + 165888;                 // 4 x 82,944
    unsigned short* wdB     = wBoff + 4 * 82944;              // 4 x 27,648
    // total 7,097,856 ushorts = 14.2 MB

    prep_all<<<dim3(648, 10), 256, 0, stream>>>(
        w_bot, w_off[0], w_off[1], w_off[2], w_off[3],
        w_d[0], w_d[1], w_d[2], w_d[3],
        wBbot, wBoff, wdB, in_nhwc, featA, featB);
    pack_nhwc<<<1536, 256, 0, stream>>>(X1, X2, in_nhwc);
    conv_mfma<6, false><<<512, 256, 0, stream>>>(in_nhwc, wBbot, featA);

    unsigned short* cur = featA;
    unsigned short* nxt = featB;
    for (int it = 0; it < 4; ++it) {
        void* outp = (it == 3) ? d_out : (void*)nxt;
        offdcn_kernel<<<256, 512, 0, stream>>>(cur, wBoff + it * 82944,
                                               wdB + it * 27648, b_d[it],
                                               outp, it == 3 ? 1 : 0);
        unsigned short* t = cur; cur = nxt; nxt = t;
    }
}